// Round 7
// baseline (287.787 us; speedup 1.0000x reference)
//
#include <hip/hip_runtime.h>

constexpr int L = 128;
constexpr int NVOX = L * L * L;          // 2097152 voxels

union HU { unsigned short u; _Float16 h; };

__device__ __forceinline__ float hbits2f(unsigned int bits) {
    HU c; c.u = (unsigned short)bits; return (float)c.h;
}

// ---- pre-pass: fp32 volume -> fp16 copy in d_ws (4 MB, fits per-XCD L2) ----
__global__ __launch_bounds__(256) void vol_to_half(
    const float* __restrict__ vol, unsigned short* __restrict__ vh)
{
    const int i = (blockIdx.x * 256 + threadIdx.x) * 4;
    const float4 f = *(const float4*)(vol + i);
    HU a, b, c, d;
    a.h = (_Float16)f.x; b.h = (_Float16)f.y;
    c.h = (_Float16)f.z; d.h = (_Float16)f.w;
    ushort4 o; o.x = a.u; o.y = b.u; o.z = c.u; o.w = d.u;
    *(ushort4*)(vh + i) = o;
}

// ---------------- fp16-gather main kernel ----------------
struct Px {
    int ub00, ub01, ub10, ub11;   // uint-index of (z,y) row base (elems/2)
    int xh, odd;                  // xe>>1, xe&1
    float wa, wb, wy0, wy1, wz0, wz1;
    bool alive;
};

__device__ __forceinline__ Px setup_px(float lj, float cx, float cy, float cz,
                                       float R00, float R01, float R02, bool vis)
{
    Px p;
    const float gx = (lj * R00 + cx) * 63.5f;
    const float gy = (lj * R01 + cy) * 63.5f;
    const float gz = (lj * R02 + cz) * 63.5f;
    const float fx0 = floorf(gx), fy0 = floorf(gy), fz0 = floorf(gz);
    const int ix = (int)fx0, iy = (int)fy0, iz = (int)fz0;
    const float fx = gx - fx0, fy = gy - fy0, fz = gz - fz0;

    const float wx0 = ((unsigned)ix       < 128u) ? 1.0f - fx : 0.0f;
    const float wx1 = ((unsigned)(ix + 1) < 128u) ? fx        : 0.0f;
    // weights mapped onto gathered pair (v[xe], v[xe+1])
    p.wa = (ix == -1) ? wx1 : ((ix == 127) ? 0.0f : wx0);
    p.wb = (ix == 127) ? wx0 : ((ix == -1) ? 0.0f : wx1);
    p.wy0 = ((unsigned)iy       < 128u) ? 1.0f - fy : 0.0f;
    p.wy1 = ((unsigned)(iy + 1) < 128u) ? fy        : 0.0f;
    p.wz0 = (vis && (unsigned)iz       < 128u) ? 1.0f - fz : 0.0f;
    p.wz1 = (vis && (unsigned)(iz + 1) < 128u) ? fz        : 0.0f;

    p.alive = vis && (ix >= -1) && (ix <= 127) && (iy >= -1) && (iy <= 127)
                  && (iz >= -1) && (iz <= 127);

    int xe = min(max(ix, 0), 126);
    int y0 = min(max(iy, 0), 127), y1 = min(max(iy + 1, 0), 127);
    int z0 = min(max(iz, 0), 127), z1 = min(max(iz + 1, 0), 127);
    if (!p.alive) { xe = 0; y0 = 0; y1 = 0; z0 = 0; z1 = 0; }  // dead -> word 0
    p.xh  = xe >> 1;
    p.odd = xe & 1;
    // row base in uint words: ((z<<14)|(y<<7)) >> 1
    p.ub00 = ((z0 << 14) | (y0 << 7)) >> 1;
    p.ub01 = ((z0 << 14) | (y1 << 7)) >> 1;
    p.ub10 = ((z1 << 14) | (y0 << 7)) >> 1;
    p.ub11 = ((z1 << 14) | (y1 << 7)) >> 1;
    return p;
}

// consume one pixel's 8 words: (w0,w1) per (y,z) combo
__device__ __forceinline__ float combine_px(const Px& p, const unsigned int* w)
{
    const int sh  = p.odd << 4;       // v[xe]  lives at bit sh of w0
    const int shc = 16 ^ sh;          // v[xe+1] lives at bit shc of w1
    float r[4];
    #pragma unroll
    for (int q = 0; q < 4; ++q) {
        const float v0 = hbits2f(w[2 * q]     >> sh);
        const float v1 = hbits2f(w[2 * q + 1] >> shc);
        r[q] = p.wa * v0 + p.wb * v1;
    }
    return p.wz0 * (p.wy0 * r[0] + p.wy1 * r[1])
         + p.wz1 * (p.wy0 * r[2] + p.wy1 * r[3]);
}

// Tile 64(k) x 16(j); 4 waves; wave wv owns rows jt*16+wv*4+0..3; lane -> k.
// All 32 word-loads (4 rows x 4 (y,z) combos x 2 words) issued back-to-back,
// fenced by sched_barrier(0). Gather source is the fp16 volume (4 MB -> L2-
// resident per XCD: ~200cy miss latency instead of 500-900 to L3/HBM).
__global__ __launch_bounds__(256) void xfel_proj_h(
    const float* __restrict__ rotmat,          // [B,3,3]
    const unsigned short* __restrict__ vh,     // [L,L,L] fp16
    float* __restrict__ out)                   // [B,L,L]
{
    const int tid  = threadIdx.x;
    const int lane = tid & 63;
    const int wv   = tid >> 6;
    const int t    = blockIdx.x;                  // 2 khalf x 8 jtile
    const int b    = blockIdx.y;
    const int k    = ((t & 1) << 6) | lane;
    const int j0   = ((t >> 1) << 4) + (wv << 2);

    const int obase = (b * L + j0) * L + k;

    const float stepw = 128.0f / 127.0f;
    const float ak  = (float)(k - 64) * stepw;
    const float ak2 = ak * ak;
    const float thr = 57.6f * 57.6f;

    bool vis[4];
    bool any_vis = false;
    #pragma unroll
    for (int m = 0; m < 4; ++m) {
        const float aj = (float)(j0 + m - 64) * stepw;
        vis[m] = (aj * aj + ak2 < thr);
        any_vis |= vis[m];
    }
    if (__ballot((int)any_vis) == 0ull) {
        #pragma unroll
        for (int m = 0; m < 4; ++m)
            __builtin_nontemporal_store(0.0f, out + obase + m * L);
        return;
    }

    const float* __restrict__ R = rotmat + b * 9;
    const float R00 = R[0], R01 = R[1], R02 = R[2];
    const float R10 = R[3], R11 = R[4], R12 = R[5];
    const float R20 = R[6], R21 = R[7], R22 = R[8];

    const float lk = -1.0f + (float)k * (2.0f / 127.0f);
    const float yc = -1.0f + 64.0f * (2.0f / 127.0f);
    const float cx = yc * R10 + lk * R20 + 1.0f;
    const float cy = yc * R11 + lk * R21 + 1.0f;
    const float cz = yc * R12 + lk * R22 + 1.0f;

    const float lj0 = -1.0f + (float)j0 * (2.0f / 127.0f);

    Px p[4];
    bool any_alive = false;
    #pragma unroll
    for (int m = 0; m < 4; ++m) {
        p[m] = setup_px(lj0 + (float)m * (2.0f / 127.0f),
                        cx, cy, cz, R00, R01, R02, vis[m]);
        any_alive |= p[m].alive;
    }
    if (__ballot((int)any_alive) == 0ull) {
        #pragma unroll
        for (int m = 0; m < 4; ++m)
            __builtin_nontemporal_store(0.0f, out + obase + m * L);
        return;
    }

    const unsigned int* __restrict__ U = (const unsigned int*)vh;

    // 32 word gathers, all issued before any consumption.
    // w1 == w0's address when xe is even -> near-free (same line, often L0/L1 hit).
    unsigned int w[4][8];
    #pragma unroll
    for (int m = 0; m < 4; ++m) {
        const int xh = p[m].xh, od = p[m].odd;
        w[m][0] = U[p[m].ub00 + xh];
        w[m][1] = U[p[m].ub00 + xh + od];
        w[m][2] = U[p[m].ub01 + xh];
        w[m][3] = U[p[m].ub01 + xh + od];
        w[m][4] = U[p[m].ub10 + xh];
        w[m][5] = U[p[m].ub10 + xh + od];
        w[m][6] = U[p[m].ub11 + xh];
        w[m][7] = U[p[m].ub11 + xh + od];
    }

    __builtin_amdgcn_sched_barrier(0);   // keep all 32 loads in flight

    #pragma unroll
    for (int m = 0; m < 4; ++m) {
        const float res = combine_px(p[m], w[m]);
        __builtin_nontemporal_store(res, out + obase + m * L);
    }
}

// ---------------- fp32 fallback (R6 kernel) for small ws_size ----------------
typedef float f2v __attribute__((ext_vector_type(2), aligned(4)));

struct PxF {
    int b00, b01, b10, b11, xe;
    float wa, wb, wy0, wy1, wz0, wz1;
    bool alive;
};

__device__ __forceinline__ PxF setup_pxf(float lj, float cx, float cy, float cz,
                                         float R00, float R01, float R02, bool vis)
{
    PxF p;
    const float gx = (lj * R00 + cx) * 63.5f;
    const float gy = (lj * R01 + cy) * 63.5f;
    const float gz = (lj * R02 + cz) * 63.5f;
    const float fx0 = floorf(gx), fy0 = floorf(gy), fz0 = floorf(gz);
    const int ix = (int)fx0, iy = (int)fy0, iz = (int)fz0;
    const float fx = gx - fx0, fy = gy - fy0, fz = gz - fz0;
    const float wx0 = ((unsigned)ix       < 128u) ? 1.0f - fx : 0.0f;
    const float wx1 = ((unsigned)(ix + 1) < 128u) ? fx        : 0.0f;
    p.wa = (ix == -1) ? wx1 : ((ix == 127) ? 0.0f : wx0);
    p.wb = (ix == 127) ? wx0 : ((ix == -1) ? 0.0f : wx1);
    p.wy0 = ((unsigned)iy       < 128u) ? 1.0f - fy : 0.0f;
    p.wy1 = ((unsigned)(iy + 1) < 128u) ? fy        : 0.0f;
    p.wz0 = (vis && (unsigned)iz       < 128u) ? 1.0f - fz : 0.0f;
    p.wz1 = (vis && (unsigned)(iz + 1) < 128u) ? fz        : 0.0f;
    p.alive = vis && (ix >= -1) && (ix <= 127) && (iy >= -1) && (iy <= 127)
                  && (iz >= -1) && (iz <= 127);
    int xe = min(max(ix, 0), 126);
    int y0 = min(max(iy, 0), 127), y1 = min(max(iy + 1, 0), 127);
    int z0 = min(max(iz, 0), 127), z1 = min(max(iz + 1, 0), 127);
    if (!p.alive) { xe = 0; y0 = 0; y1 = 0; z0 = 0; z1 = 0; }
    p.xe  = xe;
    p.b00 = (z0 << 14) | (y0 << 7);
    p.b01 = (z0 << 14) | (y1 << 7);
    p.b10 = (z1 << 14) | (y0 << 7);
    p.b11 = (z1 << 14) | (y1 << 7);
    return p;
}

__global__ __launch_bounds__(256) void xfel_proj_f(
    const float* __restrict__ rotmat,
    const float* __restrict__ vol,
    float* __restrict__ out)
{
    const int tid  = threadIdx.x;
    const int lane = tid & 63;
    const int wv   = tid >> 6;
    const int t    = blockIdx.x;
    const int b    = blockIdx.y;
    const int k    = ((t & 1) << 6) | lane;
    const int j0   = ((t >> 1) << 4) + (wv << 2);
    const int obase = (b * L + j0) * L + k;

    const float stepw = 128.0f / 127.0f;
    const float ak  = (float)(k - 64) * stepw;
    const float ak2 = ak * ak;
    const float thr = 57.6f * 57.6f;

    bool vis[4]; bool any_vis = false;
    #pragma unroll
    for (int m = 0; m < 4; ++m) {
        const float aj = (float)(j0 + m - 64) * stepw;
        vis[m] = (aj * aj + ak2 < thr);
        any_vis |= vis[m];
    }
    if (__ballot((int)any_vis) == 0ull) {
        #pragma unroll
        for (int m = 0; m < 4; ++m)
            __builtin_nontemporal_store(0.0f, out + obase + m * L);
        return;
    }

    const float* __restrict__ R = rotmat + b * 9;
    const float R00 = R[0], R01 = R[1], R02 = R[2];
    const float R10 = R[3], R11 = R[4], R12 = R[5];
    const float R20 = R[6], R21 = R[7], R22 = R[8];
    const float lk = -1.0f + (float)k * (2.0f / 127.0f);
    const float yc = -1.0f + 64.0f * (2.0f / 127.0f);
    const float cx = yc * R10 + lk * R20 + 1.0f;
    const float cy = yc * R11 + lk * R21 + 1.0f;
    const float cz = yc * R12 + lk * R22 + 1.0f;
    const float lj0 = -1.0f + (float)j0 * (2.0f / 127.0f);

    PxF p[4]; bool any_alive = false;
    #pragma unroll
    for (int m = 0; m < 4; ++m) {
        p[m] = setup_pxf(lj0 + (float)m * (2.0f / 127.0f),
                         cx, cy, cz, R00, R01, R02, vis[m]);
        any_alive |= p[m].alive;
    }
    if (__ballot((int)any_alive) == 0ull) {
        #pragma unroll
        for (int m = 0; m < 4; ++m)
            __builtin_nontemporal_store(0.0f, out + obase + m * L);
        return;
    }

    f2v v[4][4];
    #pragma unroll
    for (int m = 0; m < 4; ++m) {
        v[m][0] = *(const f2v*)(vol + p[m].b00 + p[m].xe);
        v[m][1] = *(const f2v*)(vol + p[m].b01 + p[m].xe);
        v[m][2] = *(const f2v*)(vol + p[m].b10 + p[m].xe);
        v[m][3] = *(const f2v*)(vol + p[m].b11 + p[m].xe);
    }
    __builtin_amdgcn_sched_barrier(0);

    #pragma unroll
    for (int m = 0; m < 4; ++m) {
        const float r00 = p[m].wa * v[m][0].x + p[m].wb * v[m][0].y;
        const float r01 = p[m].wa * v[m][1].x + p[m].wb * v[m][1].y;
        const float r10 = p[m].wa * v[m][2].x + p[m].wb * v[m][2].y;
        const float r11 = p[m].wa * v[m][3].x + p[m].wb * v[m][3].y;
        const float res = p[m].wz0 * (p[m].wy0 * r00 + p[m].wy1 * r01)
                        + p[m].wz1 * (p[m].wy0 * r10 + p[m].wy1 * r11);
        __builtin_nontemporal_store(res, out + obase + m * L);
    }
}

extern "C" void kernel_launch(void* const* d_in, const int* in_sizes, int n_in,
                              void* d_out, int out_size, void* d_ws, size_t ws_size,
                              hipStream_t stream) {
    const float* rotmat = (const float*)d_in[0];
    const float* vol    = (const float*)d_in[1];
    float* out          = (float*)d_out;
    const int B = in_sizes[0] / 9;                // 2048
    dim3 grid(16, B);

    if (ws_size >= (size_t)NVOX * sizeof(unsigned short)) {
        unsigned short* vh = (unsigned short*)d_ws;
        vol_to_half<<<dim3(NVOX / 4 / 256), dim3(256), 0, stream>>>(vol, vh);
        xfel_proj_h<<<grid, dim3(256), 0, stream>>>(rotmat, vh, out);
    } else {
        xfel_proj_f<<<grid, dim3(256), 0, stream>>>(rotmat, vol, out);
    }
}

// Round 8
// 239.900 us; speedup vs baseline: 1.1996x; 1.1996x over previous
//
#include <hip/hip_runtime.h>

constexpr int L = 128;

typedef float f2v __attribute__((ext_vector_type(2), aligned(4)));

struct Px {
    int b00, b01, b10, b11, xe;
    float wa, wb, wy0, wy1, wz0, wz1;
    bool alive;
};

// gx,gy,gz are voxel coords (align_corners=True mapping already applied)
__device__ __forceinline__ Px setup_g(float gx, float gy, float gz, bool vis)
{
    Px p;
    const float fx0 = floorf(gx), fy0 = floorf(gy), fz0 = floorf(gz);
    const int ix = (int)fx0, iy = (int)fy0, iz = (int)fz0;
    const float fx = gx - fx0, fy = gy - fy0, fz = gz - fz0;

    const float wx0 = ((unsigned)ix       < 128u) ? 1.0f - fx : 0.0f;
    const float wx1 = ((unsigned)(ix + 1) < 128u) ? fx        : 0.0f;
    // weights mapped onto gathered pair (v[xe], v[xe+1]):
    //   ix in [0,126]: (wx0,wx1); ix==-1: (wx1,0); ix==127: (0,wx0)
    p.wa = (ix == -1) ? wx1 : ((ix == 127) ? 0.0f : wx0);
    p.wb = (ix == 127) ? wx0 : ((ix == -1) ? 0.0f : wx1);
    p.wy0 = ((unsigned)iy       < 128u) ? 1.0f - fy : 0.0f;
    p.wy1 = ((unsigned)(iy + 1) < 128u) ? fy        : 0.0f;
    p.wz0 = (vis && (unsigned)iz       < 128u) ? 1.0f - fz : 0.0f;
    p.wz1 = (vis && (unsigned)(iz + 1) < 128u) ? fz        : 0.0f;

    p.alive = vis && (ix >= -1) && (ix <= 127) && (iy >= -1) && (iy <= 127)
                  && (iz >= -1) && (iz <= 127);

    int xe = min(max(ix, 0), 126);
    int y0 = min(max(iy, 0), 127), y1 = min(max(iy + 1, 0), 127);
    int z0 = min(max(iz, 0), 127), z1 = min(max(iz + 1, 0), 127);
    if (!p.alive) { xe = 0; y0 = 0; y1 = 0; z0 = 0; z1 = 0; }  // dead -> line 0
    p.xe  = xe;
    p.b00 = (z0 << 14) | (y0 << 7);
    p.b01 = (z0 << 14) | (y1 << 7);
    p.b10 = (z1 << 14) | (y0 << 7);
    p.b11 = (z1 << 14) | (y1 << 7);
    return p;
}

// Block = 128 threads = 2 waves (fine workgroup granularity: 16 WGs/CU x 2
// waves = full 32-wave ceiling, fast recycling of early-exit waves).
// Wave wv owns rows j0..j0+3 of a 64k x 8j tile; lane -> k (64 consecutive k
// in one row per gather: compact line footprint). All 16 paired gathers are
// issued back-to-back and fenced by sched_barrier(0).
// Per-row voxel-coord increment is exactly (R00,R01,R02): (2/127)*63.5 == 1.
__global__ __launch_bounds__(128) void xfel_proj(
    const float* __restrict__ rotmat,   // [B,3,3]
    const float* __restrict__ vol,      // [L,L,L] as [D,H,W]
    float* __restrict__ out)            // [B,L,L]
{
    const int tid  = threadIdx.x;
    const int lane = tid & 63;
    const int wv   = tid >> 6;                    // 0..1
    const int t    = blockIdx.x;                  // 0..31: 2 khalf x 16 jtile
    const int b    = blockIdx.y;
    const int k    = ((t & 1) << 6) | lane;
    const int j0   = ((t >> 1) << 3) + (wv << 2); // rows j0..j0+3

    const int obase = (b * L + j0) * L + k;

    // circular mask
    const float stepw = 128.0f / 127.0f;
    const float ak  = (float)(k - 64) * stepw;
    const float ak2 = ak * ak;
    const float thr = 57.6f * 57.6f;              // (0.9*L/2)^2

    bool vis[4];
    bool any_vis = false;
    #pragma unroll
    for (int m = 0; m < 4; ++m) {
        const float aj = (float)(j0 + m - 64) * stepw;
        vis[m] = (aj * aj + ak2 < thr);
        any_vis |= vis[m];
    }
    if (__ballot((int)any_vis) == 0ull) {         // whole wave masked
        #pragma unroll
        for (int m = 0; m < 4; ++m)
            __builtin_nontemporal_store(0.0f, out + obase + m * L);
        return;
    }

    // rotation is block-uniform -> scalar loads
    const float* __restrict__ R = rotmat + b * 9;
    const float R00 = R[0], R01 = R[1], R02 = R[2];
    const float R10 = R[3], R11 = R[4], R12 = R[5];
    const float R20 = R[6], R21 = R[7], R22 = R[8];

    const float lk = -1.0f + (float)k * (2.0f / 127.0f);
    const float yc = -1.0f + 64.0f * (2.0f / 127.0f);   // lin[64]
    const float lj0 = -1.0f + (float)j0 * (2.0f / 127.0f);

    // voxel coords of row j0; per-row increment is exactly (R00,R01,R02)
    float gx = (lj0 * R00 + yc * R10 + lk * R20 + 1.0f) * 63.5f;
    float gy = (lj0 * R01 + yc * R11 + lk * R21 + 1.0f) * 63.5f;
    float gz = (lj0 * R02 + yc * R12 + lk * R22 + 1.0f) * 63.5f;

    Px p[4];
    bool any_alive = false;
    #pragma unroll
    for (int m = 0; m < 4; ++m) {
        p[m] = setup_g(gx, gy, gz, vis[m]);
        any_alive |= p[m].alive;
        gx += R00; gy += R01; gz += R02;
    }
    if (__ballot((int)any_alive) == 0ull) {       // whole wave outside volume
        #pragma unroll
        for (int m = 0; m < 4; ++m)
            __builtin_nontemporal_store(0.0f, out + obase + m * L);
        return;
    }

    // 16 paired gathers, all issued before any consumption
    f2v v[4][4];
    #pragma unroll
    for (int m = 0; m < 4; ++m) {
        v[m][0] = *(const f2v*)(vol + p[m].b00 + p[m].xe);
        v[m][1] = *(const f2v*)(vol + p[m].b01 + p[m].xe);
        v[m][2] = *(const f2v*)(vol + p[m].b10 + p[m].xe);
        v[m][3] = *(const f2v*)(vol + p[m].b11 + p[m].xe);
    }

    __builtin_amdgcn_sched_barrier(0);   // keep all 16 loads in flight

    #pragma unroll
    for (int m = 0; m < 4; ++m) {
        const float r00 = p[m].wa * v[m][0].x + p[m].wb * v[m][0].y;
        const float r01 = p[m].wa * v[m][1].x + p[m].wb * v[m][1].y;
        const float r10 = p[m].wa * v[m][2].x + p[m].wb * v[m][2].y;
        const float r11 = p[m].wa * v[m][3].x + p[m].wb * v[m][3].y;
        const float res = p[m].wz0 * (p[m].wy0 * r00 + p[m].wy1 * r01)
                        + p[m].wz1 * (p[m].wy0 * r10 + p[m].wy1 * r11);
        __builtin_nontemporal_store(res, out + obase + m * L);
    }
}

extern "C" void kernel_launch(void* const* d_in, const int* in_sizes, int n_in,
                              void* d_out, int out_size, void* d_ws, size_t ws_size,
                              hipStream_t stream) {
    const float* rotmat = (const float*)d_in[0];
    const float* vol    = (const float*)d_in[1];
    float* out          = (float*)d_out;
    const int B = in_sizes[0] / 9;                // 2048
    dim3 grid(32, B);                             // 2 khalf x 16 jtile
    xfel_proj<<<grid, dim3(128), 0, stream>>>(rotmat, vol, out);
}

// Round 9
// 170.034 us; speedup vs baseline: 1.6925x; 1.4109x over previous
//
#include <hip/hip_runtime.h>

constexpr int L = 128;
constexpr int NVOX = L * L * L;                    // 2,097,152
constexpr size_t TAB_BYTES = (size_t)NVOX * 16;    // 32 MB packed table

union HU { unsigned short u; _Float16 h; };

__device__ __forceinline__ unsigned int pack2(float a, float b) {
    HU x, y; x.h = (_Float16)a; y.h = (_Float16)b;
    return (unsigned int)x.u | ((unsigned int)y.u << 16);
}
__device__ __forceinline__ float f16lo(unsigned int w) {
    HU c; c.u = (unsigned short)w; return (float)c.h;
}
__device__ __forceinline__ float f16hi(unsigned int w) {
    HU c; c.u = (unsigned short)(w >> 16); return (float)c.h;
}

// ---- pre-pass: T[z][y][x] = 2x2x2 stencil at (z,y,x), clamped-duplicate ----
// slot order: bit0=x, bit1=y, bit2=z ->
//   .x = (v[z][y][x],   v[z][y][x1]),  .y = (v[z][y1][x],  v[z][y1][x1])
//   .z = (v[z1][y][x],  v[z1][y][x1]), .w = (v[z1][y1][x], v[z1][y1][x1])
__global__ __launch_bounds__(256) void build_tab(
    const float* __restrict__ vol, uint4* __restrict__ T)
{
    const int e = blockIdx.x * 256 + threadIdx.x;      // 0..NVOX-1
    const int x  = e & 127, y = (e >> 7) & 127, z = e >> 14;
    const int x1 = min(x + 1, 127);
    const int ro0 = (y << 7), ro1 = (min(y + 1, 127) << 7);
    const float* __restrict__ p0 = vol + (z << 14);
    const float* __restrict__ p1 = vol + (min(z + 1, 127) << 14);
    uint4 o;
    o.x = pack2(p0[ro0 | x], p0[ro0 | x1]);
    o.y = pack2(p0[ro1 | x], p0[ro1 | x1]);
    o.z = pack2(p1[ro0 | x], p1[ro0 | x1]);
    o.w = pack2(p1[ro1 | x], p1[ro1 | x1]);
    T[e] = o;
}

// ---------------- packed-table main kernel ----------------
struct Px {
    int e;                            // table entry index (clamped base corner)
    float xa, xb, ya, yb, za, zb;     // slot-pair weights per axis
};

__device__ __forceinline__ Px setup_g(float gx, float gy, float gz, bool vis)
{
    Px p;
    const float fx0 = floorf(gx), fy0 = floorf(gy), fz0 = floorf(gz);
    const int ix = (int)fx0, iy = (int)fy0, iz = (int)fz0;
    const float fx = gx - fx0, fy = gy - fy0, fz = gz - fz0;

    // corner-validity weights (zeros padding semantics)
    const float wx0 = ((unsigned)ix       < 128u) ? 1.0f - fx : 0.0f;
    const float wx1 = ((unsigned)(ix + 1) < 128u) ? fx        : 0.0f;
    const float wy0 = ((unsigned)iy       < 128u) ? 1.0f - fy : 0.0f;
    const float wy1 = ((unsigned)(iy + 1) < 128u) ? fy        : 0.0f;
    const float wz0 = ((unsigned)iz       < 128u) ? 1.0f - fz : 0.0f;
    const float wz1 = ((unsigned)(iz + 1) < 128u) ? fz        : 0.0f;

    // map corner weights onto table slots at entry clamp(i,0,127):
    //   i==-1: slot0 holds corner i+1 -> (a,b)=(w1,0); else (a,b)=(w0,w1)
    //   (i==127: slot1 is a clamped duplicate, but w1==0 there already)
    p.xa = (ix == -1) ? wx1 : wx0;  p.xb = (ix == -1) ? 0.0f : wx1;
    p.ya = (iy == -1) ? wy1 : wy0;  p.yb = (iy == -1) ? 0.0f : wy1;
    p.za = (iz == -1) ? wz1 : wz0;  p.zb = (iz == -1) ? 0.0f : wz1;
    if (!vis) { p.za = 0.0f; p.zb = 0.0f; }           // circular mask

    const bool alive = vis && (ix >= -1) && (ix <= 127) && (iy >= -1)
                           && (iy <= 127) && (iz >= -1) && (iz <= 127);
    const int xe = min(max(ix, 0), 127);
    const int ye = min(max(iy, 0), 127);
    const int ze = min(max(iz, 0), 127);
    p.e = alive ? ((ze << 14) | (ye << 7) | xe) : 0;  // dead -> line 0
    return p;
}

__device__ __forceinline__ float combine_px(const Px& p, uint4 W)
{
    const float r0 = p.ya * (p.xa * f16lo(W.x) + p.xb * f16hi(W.x))
                   + p.yb * (p.xa * f16lo(W.y) + p.xb * f16hi(W.y));
    const float r1 = p.ya * (p.xa * f16lo(W.z) + p.xb * f16hi(W.z))
                   + p.yb * (p.xa * f16lo(W.w) + p.xb * f16hi(W.w));
    return p.za * r0 + p.zb * r1;
}

// Tile 64(k) x 16(j); 256 threads = 4 waves; wave wv owns rows jt*16+wv*4+0..3;
// lane -> k. ONE dwordx4 gather per pixel (the whole 2x2x2 stencil): the y-
// and z-corner pairs that used to live 512B / 64KB apart (separate L1 line
// transactions) now arrive in the same 16B lane request -> ~3.4x fewer line
// transactions, which R1-R8 showed is the binding resource. 4 gathers/thread
// batched ahead of a sched_barrier(0) fence.
__global__ __launch_bounds__(256) void xfel_proj_t(
    const float* __restrict__ rotmat,          // [B,3,3]
    const uint4* __restrict__ T,               // packed stencil table
    float* __restrict__ out)                   // [B,L,L]
{
    const int tid  = threadIdx.x;
    const int lane = tid & 63;
    const int wv   = tid >> 6;                    // 0..3
    const int t    = blockIdx.x;                  // 0..15: 2 khalf x 8 jtile
    const int b    = blockIdx.y;
    const int k    = ((t & 1) << 6) | lane;
    const int j0   = ((t >> 1) << 4) + (wv << 2); // rows j0..j0+3

    const int obase = (b * L + j0) * L + k;

    // circular mask
    const float stepw = 128.0f / 127.0f;
    const float ak  = (float)(k - 64) * stepw;
    const float ak2 = ak * ak;
    const float thr = 57.6f * 57.6f;              // (0.9*L/2)^2

    bool vis[4];
    bool any_vis = false;
    #pragma unroll
    for (int m = 0; m < 4; ++m) {
        const float aj = (float)(j0 + m - 64) * stepw;
        vis[m] = (aj * aj + ak2 < thr);
        any_vis |= vis[m];
    }
    if (__ballot((int)any_vis) == 0ull) {         // whole wave masked
        #pragma unroll
        for (int m = 0; m < 4; ++m)
            __builtin_nontemporal_store(0.0f, out + obase + m * L);
        return;
    }

    // rotation is block-uniform -> scalar loads
    const float* __restrict__ R = rotmat + b * 9;
    const float R00 = R[0], R01 = R[1], R02 = R[2];
    const float R10 = R[3], R11 = R[4], R12 = R[5];
    const float R20 = R[6], R21 = R[7], R22 = R[8];

    const float lk  = -1.0f + (float)k * (2.0f / 127.0f);
    const float yc  = -1.0f + 64.0f * (2.0f / 127.0f);  // lin[64]
    const float lj0 = -1.0f + (float)j0 * (2.0f / 127.0f);

    // voxel coords of row j0; per-row increment is exactly (R00,R01,R02)
    float gx = (lj0 * R00 + yc * R10 + lk * R20 + 1.0f) * 63.5f;
    float gy = (lj0 * R01 + yc * R11 + lk * R21 + 1.0f) * 63.5f;
    float gz = (lj0 * R02 + yc * R12 + lk * R22 + 1.0f) * 63.5f;

    Px p[4];
    bool any_alive = false;
    #pragma unroll
    for (int m = 0; m < 4; ++m) {
        p[m] = setup_g(gx, gy, gz, vis[m]);
        any_alive |= (p[m].e != 0);
        gx += R00; gy += R01; gz += R02;
    }
    if (__ballot((int)any_alive) == 0ull) {       // whole wave dead
        #pragma unroll
        for (int m = 0; m < 4; ++m)
            __builtin_nontemporal_store(0.0f, out + obase + m * L);
        return;
    }

    // 4 stencil gathers (one per pixel), all in flight before consumption
    uint4 W[4];
    #pragma unroll
    for (int m = 0; m < 4; ++m) W[m] = T[p[m].e];

    __builtin_amdgcn_sched_barrier(0);

    #pragma unroll
    for (int m = 0; m < 4; ++m) {
        const float res = combine_px(p[m], W[m]);
        __builtin_nontemporal_store(res, out + obase + m * L);
    }
}

// ---------------- fp32 fallback (R6 kernel) for small ws_size ----------------
typedef float f2v __attribute__((ext_vector_type(2), aligned(4)));

struct PxF {
    int b00, b01, b10, b11, xe;
    float wa, wb, wy0, wy1, wz0, wz1;
    bool alive;
};

__device__ __forceinline__ PxF setup_pxf(float gx, float gy, float gz, bool vis)
{
    PxF p;
    const float fx0 = floorf(gx), fy0 = floorf(gy), fz0 = floorf(gz);
    const int ix = (int)fx0, iy = (int)fy0, iz = (int)fz0;
    const float fx = gx - fx0, fy = gy - fy0, fz = gz - fz0;
    const float wx0 = ((unsigned)ix       < 128u) ? 1.0f - fx : 0.0f;
    const float wx1 = ((unsigned)(ix + 1) < 128u) ? fx        : 0.0f;
    p.wa = (ix == -1) ? wx1 : ((ix == 127) ? 0.0f : wx0);
    p.wb = (ix == 127) ? wx0 : ((ix == -1) ? 0.0f : wx1);
    p.wy0 = ((unsigned)iy       < 128u) ? 1.0f - fy : 0.0f;
    p.wy1 = ((unsigned)(iy + 1) < 128u) ? fy        : 0.0f;
    p.wz0 = (vis && (unsigned)iz       < 128u) ? 1.0f - fz : 0.0f;
    p.wz1 = (vis && (unsigned)(iz + 1) < 128u) ? fz        : 0.0f;
    p.alive = vis && (ix >= -1) && (ix <= 127) && (iy >= -1) && (iy <= 127)
                  && (iz >= -1) && (iz <= 127);
    int xe = min(max(ix, 0), 126);
    int y0 = min(max(iy, 0), 127), y1 = min(max(iy + 1, 0), 127);
    int z0 = min(max(iz, 0), 127), z1 = min(max(iz + 1, 0), 127);
    if (!p.alive) { xe = 0; y0 = 0; y1 = 0; z0 = 0; z1 = 0; }
    p.xe  = xe;
    p.b00 = (z0 << 14) | (y0 << 7);
    p.b01 = (z0 << 14) | (y1 << 7);
    p.b10 = (z1 << 14) | (y0 << 7);
    p.b11 = (z1 << 14) | (y1 << 7);
    return p;
}

__global__ __launch_bounds__(256) void xfel_proj_f(
    const float* __restrict__ rotmat,
    const float* __restrict__ vol,
    float* __restrict__ out)
{
    const int tid  = threadIdx.x;
    const int lane = tid & 63;
    const int wv   = tid >> 6;
    const int t    = blockIdx.x;
    const int b    = blockIdx.y;
    const int k    = ((t & 1) << 6) | lane;
    const int j0   = ((t >> 1) << 4) + (wv << 2);
    const int obase = (b * L + j0) * L + k;

    const float stepw = 128.0f / 127.0f;
    const float ak  = (float)(k - 64) * stepw;
    const float ak2 = ak * ak;
    const float thr = 57.6f * 57.6f;

    bool vis[4]; bool any_vis = false;
    #pragma unroll
    for (int m = 0; m < 4; ++m) {
        const float aj = (float)(j0 + m - 64) * stepw;
        vis[m] = (aj * aj + ak2 < thr);
        any_vis |= vis[m];
    }
    if (__ballot((int)any_vis) == 0ull) {
        #pragma unroll
        for (int m = 0; m < 4; ++m)
            __builtin_nontemporal_store(0.0f, out + obase + m * L);
        return;
    }

    const float* __restrict__ R = rotmat + b * 9;
    const float R00 = R[0], R01 = R[1], R02 = R[2];
    const float R10 = R[3], R11 = R[4], R12 = R[5];
    const float R20 = R[6], R21 = R[7], R22 = R[8];
    const float lk  = -1.0f + (float)k * (2.0f / 127.0f);
    const float yc  = -1.0f + 64.0f * (2.0f / 127.0f);
    const float lj0 = -1.0f + (float)j0 * (2.0f / 127.0f);

    float gx = (lj0 * R00 + yc * R10 + lk * R20 + 1.0f) * 63.5f;
    float gy = (lj0 * R01 + yc * R11 + lk * R21 + 1.0f) * 63.5f;
    float gz = (lj0 * R02 + yc * R12 + lk * R22 + 1.0f) * 63.5f;

    PxF p[4]; bool any_alive = false;
    #pragma unroll
    for (int m = 0; m < 4; ++m) {
        p[m] = setup_pxf(gx, gy, gz, vis[m]);
        any_alive |= p[m].alive;
        gx += R00; gy += R01; gz += R02;
    }
    if (__ballot((int)any_alive) == 0ull) {
        #pragma unroll
        for (int m = 0; m < 4; ++m)
            __builtin_nontemporal_store(0.0f, out + obase + m * L);
        return;
    }

    f2v v[4][4];
    #pragma unroll
    for (int m = 0; m < 4; ++m) {
        v[m][0] = *(const f2v*)(vol + p[m].b00 + p[m].xe);
        v[m][1] = *(const f2v*)(vol + p[m].b01 + p[m].xe);
        v[m][2] = *(const f2v*)(vol + p[m].b10 + p[m].xe);
        v[m][3] = *(const f2v*)(vol + p[m].b11 + p[m].xe);
    }
    __builtin_amdgcn_sched_barrier(0);

    #pragma unroll
    for (int m = 0; m < 4; ++m) {
        const float r00 = p[m].wa * v[m][0].x + p[m].wb * v[m][0].y;
        const float r01 = p[m].wa * v[m][1].x + p[m].wb * v[m][1].y;
        const float r10 = p[m].wa * v[m][2].x + p[m].wb * v[m][2].y;
        const float r11 = p[m].wa * v[m][3].x + p[m].wb * v[m][3].y;
        const float res = p[m].wz0 * (p[m].wy0 * r00 + p[m].wy1 * r01)
                        + p[m].wz1 * (p[m].wy0 * r10 + p[m].wy1 * r11);
        __builtin_nontemporal_store(res, out + obase + m * L);
    }
}

extern "C" void kernel_launch(void* const* d_in, const int* in_sizes, int n_in,
                              void* d_out, int out_size, void* d_ws, size_t ws_size,
                              hipStream_t stream) {
    const float* rotmat = (const float*)d_in[0];
    const float* vol    = (const float*)d_in[1];
    float* out          = (float*)d_out;
    const int B = in_sizes[0] / 9;                // 2048
    dim3 grid(16, B);                             // 2 khalf x 8 jtile

    if (ws_size >= TAB_BYTES) {
        uint4* T = (uint4*)d_ws;
        build_tab<<<dim3(NVOX / 256), dim3(256), 0, stream>>>(vol, T);
        xfel_proj_t<<<grid, dim3(256), 0, stream>>>(rotmat, T, out);
    } else {
        xfel_proj_f<<<grid, dim3(256), 0, stream>>>(rotmat, vol, out);
    }
}

// Round 10
// 159.236 us; speedup vs baseline: 1.8073x; 1.0678x over previous
//
#include <hip/hip_runtime.h>

constexpr int L = 128;
constexpr int NVOX = L * L * L;                    // 2,097,152
constexpr size_t TAB_BYTES = (size_t)NVOX * 16;    // 32 MB packed table

union HU { unsigned short u; _Float16 h; };

__device__ __forceinline__ unsigned int pack2(float a, float b) {
    HU x, y; x.h = (_Float16)a; y.h = (_Float16)b;
    return (unsigned int)x.u | ((unsigned int)y.u << 16);
}
__device__ __forceinline__ float f16lo(unsigned int w) {
    HU c; c.u = (unsigned short)w; return (float)c.h;
}
__device__ __forceinline__ float f16hi(unsigned int w) {
    HU c; c.u = (unsigned short)(w >> 16); return (float)c.h;
}

// ---- pre-pass: T[z][y][x] = 2x2x2 stencil at (z,y,x), clamped-duplicate ----
__global__ __launch_bounds__(256) void build_tab(
    const float* __restrict__ vol, uint4* __restrict__ T)
{
    const int e = blockIdx.x * 256 + threadIdx.x;      // 0..NVOX-1
    const int x  = e & 127, y = (e >> 7) & 127, z = e >> 14;
    const int x1 = min(x + 1, 127);
    const int ro0 = (y << 7), ro1 = (min(y + 1, 127) << 7);
    const float* __restrict__ p0 = vol + (z << 14);
    const float* __restrict__ p1 = vol + (min(z + 1, 127) << 14);
    uint4 o;
    o.x = pack2(p0[ro0 | x], p0[ro0 | x1]);
    o.y = pack2(p0[ro1 | x], p0[ro1 | x1]);
    o.z = pack2(p1[ro0 | x], p1[ro0 | x1]);
    o.w = pack2(p1[ro1 | x], p1[ro1 | x1]);
    T[e] = o;
}

// ---------------- packed-table main kernel ----------------
struct Px {
    int e;                            // table entry index (clamped base corner)
    float xa, xb, ya, yb, za, zb;     // slot-pair weights per axis
};

__device__ __forceinline__ Px setup_g(float gx, float gy, float gz, bool vis)
{
    Px p;
    const float fx0 = floorf(gx), fy0 = floorf(gy), fz0 = floorf(gz);
    const int ix = (int)fx0, iy = (int)fy0, iz = (int)fz0;
    const float fx = gx - fx0, fy = gy - fy0, fz = gz - fz0;

    const float wx0 = ((unsigned)ix       < 128u) ? 1.0f - fx : 0.0f;
    const float wx1 = ((unsigned)(ix + 1) < 128u) ? fx        : 0.0f;
    const float wy0 = ((unsigned)iy       < 128u) ? 1.0f - fy : 0.0f;
    const float wy1 = ((unsigned)(iy + 1) < 128u) ? fy        : 0.0f;
    const float wz0 = ((unsigned)iz       < 128u) ? 1.0f - fz : 0.0f;
    const float wz1 = ((unsigned)(iz + 1) < 128u) ? fz        : 0.0f;

    // map corner weights onto table slots at entry clamp(i,0,127)
    p.xa = (ix == -1) ? wx1 : wx0;  p.xb = (ix == -1) ? 0.0f : wx1;
    p.ya = (iy == -1) ? wy1 : wy0;  p.yb = (iy == -1) ? 0.0f : wy1;
    p.za = (iz == -1) ? wz1 : wz0;  p.zb = (iz == -1) ? 0.0f : wz1;
    if (!vis) { p.za = 0.0f; p.zb = 0.0f; }           // circular mask

    const bool alive = vis && (ix >= -1) && (ix <= 127) && (iy >= -1)
                           && (iy <= 127) && (iz >= -1) && (iz <= 127);
    const int xe = min(max(ix, 0), 127);
    const int ye = min(max(iy, 0), 127);
    const int ze = min(max(iz, 0), 127);
    p.e = alive ? ((ze << 14) | (ye << 7) | xe) : 0;  // dead -> line 0
    return p;
}

__device__ __forceinline__ float combine_px(const Px& p, uint4 W)
{
    const float r0 = p.ya * (p.xa * f16lo(W.x) + p.xb * f16hi(W.x))
                   + p.yb * (p.xa * f16lo(W.y) + p.xb * f16hi(W.y));
    const float r1 = p.ya * (p.xa * f16lo(W.z) + p.xb * f16hi(W.z))
                   + p.yb * (p.xa * f16lo(W.w) + p.xb * f16hi(W.w));
    return p.za * r0 + p.zb * r1;
}

// XCD-aware swizzle: the table entries an image touches form a 2-voxel-thick
// plane; its 64B lines are shared between the image's 16 tiles. Hardware
// round-robins consecutive block IDs across the 8 XCDs, so with a (16,B) grid
// sibling tiles land on DIFFERENT XCDs and each XCD re-fetches the shared
// lines (2.1x line waste, FETCH=445MB vs ~215MB compulsory). Remap: block n ->
// XCD n&7 keeps all 16 tiles of an image on one XCD, ~6 images in flight per
// XCD (~2.5MB of plane lines < 4MB L2) -> sibling-entry fetches become L2 hits.
__global__ __launch_bounds__(256) void xfel_proj_t(
    const float* __restrict__ rotmat,          // [B,3,3]
    const uint4* __restrict__ T,               // packed stencil table
    float* __restrict__ out,                   // [B,L,L]
    int nimg_per_xcd)                          // B/8 (0 -> identity mapping)
{
    const int n = blockIdx.x;
    int b, t;
    if (nimg_per_xcd > 0) {
        const int xcd = n & 7;
        const int s   = n >> 3;                   // 0 .. 16*B/8-1
        b = xcd * nimg_per_xcd + (s >> 4);
        t = s & 15;
    } else {
        b = n >> 4;
        t = n & 15;
    }

    const int tid  = threadIdx.x;
    const int lane = tid & 63;
    const int wv   = tid >> 6;                    // 0..3
    const int k    = ((t & 1) << 6) | lane;
    const int j0   = ((t >> 1) << 4) + (wv << 2); // rows j0..j0+3

    const int obase = (b * L + j0) * L + k;

    // circular mask
    const float stepw = 128.0f / 127.0f;
    const float ak  = (float)(k - 64) * stepw;
    const float ak2 = ak * ak;
    const float thr = 57.6f * 57.6f;              // (0.9*L/2)^2

    bool vis[4];
    bool any_vis = false;
    #pragma unroll
    for (int m = 0; m < 4; ++m) {
        const float aj = (float)(j0 + m - 64) * stepw;
        vis[m] = (aj * aj + ak2 < thr);
        any_vis |= vis[m];
    }
    if (__ballot((int)any_vis) == 0ull) {         // whole wave masked
        #pragma unroll
        for (int m = 0; m < 4; ++m)
            __builtin_nontemporal_store(0.0f, out + obase + m * L);
        return;
    }

    // rotation is block-uniform -> scalar loads
    const float* __restrict__ R = rotmat + b * 9;
    const float R00 = R[0], R01 = R[1], R02 = R[2];
    const float R10 = R[3], R11 = R[4], R12 = R[5];
    const float R20 = R[6], R21 = R[7], R22 = R[8];

    const float lk  = -1.0f + (float)k * (2.0f / 127.0f);
    const float yc  = -1.0f + 64.0f * (2.0f / 127.0f);  // lin[64]
    const float lj0 = -1.0f + (float)j0 * (2.0f / 127.0f);

    // voxel coords of row j0; per-row increment is exactly (R00,R01,R02)
    float gx = (lj0 * R00 + yc * R10 + lk * R20 + 1.0f) * 63.5f;
    float gy = (lj0 * R01 + yc * R11 + lk * R21 + 1.0f) * 63.5f;
    float gz = (lj0 * R02 + yc * R12 + lk * R22 + 1.0f) * 63.5f;

    Px p[4];
    bool any_alive = false;
    #pragma unroll
    for (int m = 0; m < 4; ++m) {
        p[m] = setup_g(gx, gy, gz, vis[m]);
        any_alive |= (p[m].e != 0);
        gx += R00; gy += R01; gz += R02;
    }
    if (__ballot((int)any_alive) == 0ull) {       // whole wave dead
        #pragma unroll
        for (int m = 0; m < 4; ++m)
            __builtin_nontemporal_store(0.0f, out + obase + m * L);
        return;
    }

    // 4 stencil gathers (one per pixel), all in flight before consumption
    uint4 W[4];
    #pragma unroll
    for (int m = 0; m < 4; ++m) W[m] = T[p[m].e];

    __builtin_amdgcn_sched_barrier(0);

    #pragma unroll
    for (int m = 0; m < 4; ++m) {
        const float res = combine_px(p[m], W[m]);
        __builtin_nontemporal_store(res, out + obase + m * L);
    }
}

// ---------------- fp32 fallback (R6 kernel) for small ws_size ----------------
typedef float f2v __attribute__((ext_vector_type(2), aligned(4)));

struct PxF {
    int b00, b01, b10, b11, xe;
    float wa, wb, wy0, wy1, wz0, wz1;
    bool alive;
};

__device__ __forceinline__ PxF setup_pxf(float gx, float gy, float gz, bool vis)
{
    PxF p;
    const float fx0 = floorf(gx), fy0 = floorf(gy), fz0 = floorf(gz);
    const int ix = (int)fx0, iy = (int)fy0, iz = (int)fz0;
    const float fx = gx - fx0, fy = gy - fy0, fz = gz - fz0;
    const float wx0 = ((unsigned)ix       < 128u) ? 1.0f - fx : 0.0f;
    const float wx1 = ((unsigned)(ix + 1) < 128u) ? fx        : 0.0f;
    p.wa = (ix == -1) ? wx1 : ((ix == 127) ? 0.0f : wx0);
    p.wb = (ix == 127) ? wx0 : ((ix == -1) ? 0.0f : wx1);
    p.wy0 = ((unsigned)iy       < 128u) ? 1.0f - fy : 0.0f;
    p.wy1 = ((unsigned)(iy + 1) < 128u) ? fy        : 0.0f;
    p.wz0 = (vis && (unsigned)iz       < 128u) ? 1.0f - fz : 0.0f;
    p.wz1 = (vis && (unsigned)(iz + 1) < 128u) ? fz        : 0.0f;
    p.alive = vis && (ix >= -1) && (ix <= 127) && (iy >= -1) && (iy <= 127)
                  && (iz >= -1) && (iz <= 127);
    int xe = min(max(ix, 0), 126);
    int y0 = min(max(iy, 0), 127), y1 = min(max(iy + 1, 0), 127);
    int z0 = min(max(iz, 0), 127), z1 = min(max(iz + 1, 0), 127);
    if (!p.alive) { xe = 0; y0 = 0; y1 = 0; z0 = 0; z1 = 0; }
    p.xe  = xe;
    p.b00 = (z0 << 14) | (y0 << 7);
    p.b01 = (z0 << 14) | (y1 << 7);
    p.b10 = (z1 << 14) | (y0 << 7);
    p.b11 = (z1 << 14) | (y1 << 7);
    return p;
}

__global__ __launch_bounds__(256) void xfel_proj_f(
    const float* __restrict__ rotmat,
    const float* __restrict__ vol,
    float* __restrict__ out)
{
    const int tid  = threadIdx.x;
    const int lane = tid & 63;
    const int wv   = tid >> 6;
    const int t    = blockIdx.x;
    const int b    = blockIdx.y;
    const int k    = ((t & 1) << 6) | lane;
    const int j0   = ((t >> 1) << 4) + (wv << 2);
    const int obase = (b * L + j0) * L + k;

    const float stepw = 128.0f / 127.0f;
    const float ak  = (float)(k - 64) * stepw;
    const float ak2 = ak * ak;
    const float thr = 57.6f * 57.6f;

    bool vis[4]; bool any_vis = false;
    #pragma unroll
    for (int m = 0; m < 4; ++m) {
        const float aj = (float)(j0 + m - 64) * stepw;
        vis[m] = (aj * aj + ak2 < thr);
        any_vis |= vis[m];
    }
    if (__ballot((int)any_vis) == 0ull) {
        #pragma unroll
        for (int m = 0; m < 4; ++m)
            __builtin_nontemporal_store(0.0f, out + obase + m * L);
        return;
    }

    const float* __restrict__ R = rotmat + b * 9;
    const float R00 = R[0], R01 = R[1], R02 = R[2];
    const float R10 = R[3], R11 = R[4], R12 = R[5];
    const float R20 = R[6], R21 = R[7], R22 = R[8];
    const float lk  = -1.0f + (float)k * (2.0f / 127.0f);
    const float yc  = -1.0f + 64.0f * (2.0f / 127.0f);
    const float lj0 = -1.0f + (float)j0 * (2.0f / 127.0f);

    float gx = (lj0 * R00 + yc * R10 + lk * R20 + 1.0f) * 63.5f;
    float gy = (lj0 * R01 + yc * R11 + lk * R21 + 1.0f) * 63.5f;
    float gz = (lj0 * R02 + yc * R12 + lk * R22 + 1.0f) * 63.5f;

    PxF p[4]; bool any_alive = false;
    #pragma unroll
    for (int m = 0; m < 4; ++m) {
        p[m] = setup_pxf(gx, gy, gz, vis[m]);
        any_alive |= p[m].alive;
        gx += R00; gy += R01; gz += R02;
    }
    if (__ballot((int)any_alive) == 0ull) {
        #pragma unroll
        for (int m = 0; m < 4; ++m)
            __builtin_nontemporal_store(0.0f, out + obase + m * L);
        return;
    }

    f2v v[4][4];
    #pragma unroll
    for (int m = 0; m < 4; ++m) {
        v[m][0] = *(const f2v*)(vol + p[m].b00 + p[m].xe);
        v[m][1] = *(const f2v*)(vol + p[m].b01 + p[m].xe);
        v[m][2] = *(const f2v*)(vol + p[m].b10 + p[m].xe);
        v[m][3] = *(const f2v*)(vol + p[m].b11 + p[m].xe);
    }
    __builtin_amdgcn_sched_barrier(0);

    #pragma unroll
    for (int m = 0; m < 4; ++m) {
        const float r00 = p[m].wa * v[m][0].x + p[m].wb * v[m][0].y;
        const float r01 = p[m].wa * v[m][1].x + p[m].wb * v[m][1].y;
        const float r10 = p[m].wa * v[m][2].x + p[m].wb * v[m][2].y;
        const float r11 = p[m].wa * v[m][3].x + p[m].wb * v[m][3].y;
        const float res = p[m].wz0 * (p[m].wy0 * r00 + p[m].wy1 * r01)
                        + p[m].wz1 * (p[m].wy0 * r10 + p[m].wy1 * r11);
        __builtin_nontemporal_store(res, out + obase + m * L);
    }
}

extern "C" void kernel_launch(void* const* d_in, const int* in_sizes, int n_in,
                              void* d_out, int out_size, void* d_ws, size_t ws_size,
                              hipStream_t stream) {
    const float* rotmat = (const float*)d_in[0];
    const float* vol    = (const float*)d_in[1];
    float* out          = (float*)d_out;
    const int B = in_sizes[0] / 9;                // 2048

    if (ws_size >= TAB_BYTES) {
        uint4* T = (uint4*)d_ws;
        build_tab<<<dim3(NVOX / 256), dim3(256), 0, stream>>>(vol, T);
        const int nper = (B % 8 == 0) ? (B / 8) : 0;   // 0 -> identity map
        xfel_proj_t<<<dim3(16 * B), dim3(256), 0, stream>>>(rotmat, T, out, nper);
    } else {
        xfel_proj_f<<<dim3(16, B), dim3(256), 0, stream>>>(rotmat, vol, out);
    }
}

// Round 11
// 142.991 us; speedup vs baseline: 2.0126x; 1.1136x over previous
//
#include <hip/hip_runtime.h>

constexpr int L = 128;
constexpr int NVOX = L * L * L;                    // 2,097,152
constexpr size_t TAB_BYTES = (size_t)NVOX * 16;    // 32 MB packed table

union HU { unsigned short u; _Float16 h; };

__device__ __forceinline__ unsigned int pack2(float a, float b) {
    HU x, y; x.h = (_Float16)a; y.h = (_Float16)b;
    return (unsigned int)x.u | ((unsigned int)y.u << 16);
}
__device__ __forceinline__ float f16lo(unsigned int w) {
    HU c; c.u = (unsigned short)w; return (float)c.h;
}
__device__ __forceinline__ float f16hi(unsigned int w) {
    HU c; c.u = (unsigned short)(w >> 16); return (float)c.h;
}

// Brick swizzle: 64B line = 4 entries = 2x2 (x,y) patch at one z.
// A random plane's quantized entry-set uses ~2 of 4 entries of a 1x4 x-run
// (R9/R10: FETCH stuck at 448MB = 2.1x compulsory) but more of a 2x2 patch
// -> higher line utilization -> less L2-miss fill traffic.
__device__ __forceinline__ int brick_idx(int x, int y, int z) {
    return (z << 14) | ((y >> 1) << 8) | ((x >> 1) << 2) | ((y & 1) << 1) | (x & 1);
}

// ---- pre-pass: T[e] = 2x2x2 stencil at (z,y,x), clamped-duplicate ----
// 256-thread block covers two consecutive x-rows (y even/odd pair, same z):
// every touched 64B line is fully written -> no partial-line RMW.
__global__ __launch_bounds__(256) void build_tab(
    const float* __restrict__ vol, uint4* __restrict__ T)
{
    const int e = blockIdx.x * 256 + threadIdx.x;      // linear voxel id
    const int x  = e & 127, y = (e >> 7) & 127, z = e >> 14;
    const int x1 = min(x + 1, 127);
    const int ro0 = (y << 7), ro1 = (min(y + 1, 127) << 7);
    const float* __restrict__ p0 = vol + (z << 14);
    const float* __restrict__ p1 = vol + (min(z + 1, 127) << 14);
    uint4 o;
    o.x = pack2(p0[ro0 | x], p0[ro0 | x1]);
    o.y = pack2(p0[ro1 | x], p0[ro1 | x1]);
    o.z = pack2(p1[ro0 | x], p1[ro0 | x1]);
    o.w = pack2(p1[ro1 | x], p1[ro1 | x1]);
    T[brick_idx(x, y, z)] = o;
}

// ---------------- packed-table main kernel ----------------
struct Px {
    int e;                            // bricked table index
    float xa, xb, ya, yb, za, zb;     // slot-pair weights per axis
};

__device__ __forceinline__ Px setup_g(float gx, float gy, float gz, bool vis)
{
    Px p;
    const float fx0 = floorf(gx), fy0 = floorf(gy), fz0 = floorf(gz);
    const int ix = (int)fx0, iy = (int)fy0, iz = (int)fz0;
    const float fx = gx - fx0, fy = gy - fy0, fz = gz - fz0;

    const float wx0 = ((unsigned)ix       < 128u) ? 1.0f - fx : 0.0f;
    const float wx1 = ((unsigned)(ix + 1) < 128u) ? fx        : 0.0f;
    const float wy0 = ((unsigned)iy       < 128u) ? 1.0f - fy : 0.0f;
    const float wy1 = ((unsigned)(iy + 1) < 128u) ? fy        : 0.0f;
    const float wz0 = ((unsigned)iz       < 128u) ? 1.0f - fz : 0.0f;
    const float wz1 = ((unsigned)(iz + 1) < 128u) ? fz        : 0.0f;

    // map corner weights onto table slots at entry clamp(i,0,127)
    p.xa = (ix == -1) ? wx1 : wx0;  p.xb = (ix == -1) ? 0.0f : wx1;
    p.ya = (iy == -1) ? wy1 : wy0;  p.yb = (iy == -1) ? 0.0f : wy1;
    p.za = (iz == -1) ? wz1 : wz0;  p.zb = (iz == -1) ? 0.0f : wz1;
    if (!vis) { p.za = 0.0f; p.zb = 0.0f; }           // circular mask

    const bool alive = vis && (ix >= -1) && (ix <= 127) && (iy >= -1)
                           && (iy <= 127) && (iz >= -1) && (iz <= 127);
    const int xe = min(max(ix, 0), 127);
    const int ye = min(max(iy, 0), 127);
    const int ze = min(max(iz, 0), 127);
    p.e = alive ? brick_idx(xe, ye, ze) : 0;          // dead -> line 0
    return p;
}

__device__ __forceinline__ float combine_px(const Px& p, uint4 W)
{
    const float r0 = p.ya * (p.xa * f16lo(W.x) + p.xb * f16hi(W.x))
                   + p.yb * (p.xa * f16lo(W.y) + p.xb * f16hi(W.y));
    const float r1 = p.ya * (p.xa * f16lo(W.z) + p.xb * f16hi(W.z))
                   + p.yb * (p.xa * f16lo(W.w) + p.xb * f16hi(W.w));
    return p.za * r0 + p.zb * r1;
}

// 1D grid + XCD-affine mapping (kept from R10: occupancy 66% vs 42%).
__global__ __launch_bounds__(256) void xfel_proj_t(
    const float* __restrict__ rotmat,          // [B,3,3]
    const uint4* __restrict__ T,               // packed stencil table
    float* __restrict__ out,                   // [B,L,L]
    int nimg_per_xcd)                          // B/8 (0 -> identity mapping)
{
    const int n = blockIdx.x;
    int b, t;
    if (nimg_per_xcd > 0) {
        const int xcd = n & 7;
        const int s   = n >> 3;
        b = xcd * nimg_per_xcd + (s >> 4);
        t = s & 15;
    } else {
        b = n >> 4;
        t = n & 15;
    }

    const int tid  = threadIdx.x;
    const int lane = tid & 63;
    const int wv   = tid >> 6;                    // 0..3
    const int k    = ((t & 1) << 6) | lane;
    const int j0   = ((t >> 1) << 4) + (wv << 2); // rows j0..j0+3

    const int obase = (b * L + j0) * L + k;

    // circular mask
    const float stepw = 128.0f / 127.0f;
    const float ak  = (float)(k - 64) * stepw;
    const float ak2 = ak * ak;
    const float thr = 57.6f * 57.6f;              // (0.9*L/2)^2

    bool vis[4];
    bool any_vis = false;
    #pragma unroll
    for (int m = 0; m < 4; ++m) {
        const float aj = (float)(j0 + m - 64) * stepw;
        vis[m] = (aj * aj + ak2 < thr);
        any_vis |= vis[m];
    }
    if (__ballot((int)any_vis) == 0ull) {         // whole wave masked
        #pragma unroll
        for (int m = 0; m < 4; ++m)
            __builtin_nontemporal_store(0.0f, out + obase + m * L);
        return;
    }

    // rotation is block-uniform -> scalar loads
    const float* __restrict__ R = rotmat + b * 9;
    const float R00 = R[0], R01 = R[1], R02 = R[2];
    const float R10 = R[3], R11 = R[4], R12 = R[5];
    const float R20 = R[6], R21 = R[7], R22 = R[8];

    const float lk  = -1.0f + (float)k * (2.0f / 127.0f);
    const float yc  = -1.0f + 64.0f * (2.0f / 127.0f);  // lin[64]
    const float lj0 = -1.0f + (float)j0 * (2.0f / 127.0f);

    // voxel coords of row j0; per-row increment is exactly (R00,R01,R02)
    float gx = (lj0 * R00 + yc * R10 + lk * R20 + 1.0f) * 63.5f;
    float gy = (lj0 * R01 + yc * R11 + lk * R21 + 1.0f) * 63.5f;
    float gz = (lj0 * R02 + yc * R12 + lk * R22 + 1.0f) * 63.5f;

    Px p[4];
    bool any_alive = false;
    #pragma unroll
    for (int m = 0; m < 4; ++m) {
        p[m] = setup_g(gx, gy, gz, vis[m]);
        any_alive |= (p[m].e != 0);
        gx += R00; gy += R01; gz += R02;
    }
    if (__ballot((int)any_alive) == 0ull) {       // whole wave dead
        #pragma unroll
        for (int m = 0; m < 4; ++m)
            __builtin_nontemporal_store(0.0f, out + obase + m * L);
        return;
    }

    // 4 stencil gathers (one per pixel), all in flight before consumption
    uint4 W[4];
    #pragma unroll
    for (int m = 0; m < 4; ++m) W[m] = T[p[m].e];

    __builtin_amdgcn_sched_barrier(0);

    #pragma unroll
    for (int m = 0; m < 4; ++m) {
        const float res = combine_px(p[m], W[m]);
        __builtin_nontemporal_store(res, out + obase + m * L);
    }
}

// ---------------- fp32 fallback (R6 kernel) for small ws_size ----------------
typedef float f2v __attribute__((ext_vector_type(2), aligned(4)));

struct PxF {
    int b00, b01, b10, b11, xe;
    float wa, wb, wy0, wy1, wz0, wz1;
    bool alive;
};

__device__ __forceinline__ PxF setup_pxf(float gx, float gy, float gz, bool vis)
{
    PxF p;
    const float fx0 = floorf(gx), fy0 = floorf(gy), fz0 = floorf(gz);
    const int ix = (int)fx0, iy = (int)fy0, iz = (int)fz0;
    const float fx = gx - fx0, fy = gy - fy0, fz = gz - fz0;
    const float wx0 = ((unsigned)ix       < 128u) ? 1.0f - fx : 0.0f;
    const float wx1 = ((unsigned)(ix + 1) < 128u) ? fx        : 0.0f;
    p.wa = (ix == -1) ? wx1 : ((ix == 127) ? 0.0f : wx0);
    p.wb = (ix == 127) ? wx0 : ((ix == -1) ? 0.0f : wx1);
    p.wy0 = ((unsigned)iy       < 128u) ? 1.0f - fy : 0.0f;
    p.wy1 = ((unsigned)(iy + 1) < 128u) ? fy        : 0.0f;
    p.wz0 = (vis && (unsigned)iz       < 128u) ? 1.0f - fz : 0.0f;
    p.wz1 = (vis && (unsigned)(iz + 1) < 128u) ? fz        : 0.0f;
    p.alive = vis && (ix >= -1) && (ix <= 127) && (iy >= -1) && (iy <= 127)
                  && (iz >= -1) && (iz <= 127);
    int xe = min(max(ix, 0), 126);
    int y0 = min(max(iy, 0), 127), y1 = min(max(iy + 1, 0), 127);
    int z0 = min(max(iz, 0), 127), z1 = min(max(iz + 1, 0), 127);
    if (!p.alive) { xe = 0; y0 = 0; y1 = 0; z0 = 0; z1 = 0; }
    p.xe  = xe;
    p.b00 = (z0 << 14) | (y0 << 7);
    p.b01 = (z0 << 14) | (y1 << 7);
    p.b10 = (z1 << 14) | (y0 << 7);
    p.b11 = (z1 << 14) | (y1 << 7);
    return p;
}

__global__ __launch_bounds__(256) void xfel_proj_f(
    const float* __restrict__ rotmat,
    const float* __restrict__ vol,
    float* __restrict__ out)
{
    const int tid  = threadIdx.x;
    const int lane = tid & 63;
    const int wv   = tid >> 6;
    const int t    = blockIdx.x;
    const int b    = blockIdx.y;
    const int k    = ((t & 1) << 6) | lane;
    const int j0   = ((t >> 1) << 4) + (wv << 2);
    const int obase = (b * L + j0) * L + k;

    const float stepw = 128.0f / 127.0f;
    const float ak  = (float)(k - 64) * stepw;
    const float ak2 = ak * ak;
    const float thr = 57.6f * 57.6f;

    bool vis[4]; bool any_vis = false;
    #pragma unroll
    for (int m = 0; m < 4; ++m) {
        const float aj = (float)(j0 + m - 64) * stepw;
        vis[m] = (aj * aj + ak2 < thr);
        any_vis |= vis[m];
    }
    if (__ballot((int)any_vis) == 0ull) {
        #pragma unroll
        for (int m = 0; m < 4; ++m)
            __builtin_nontemporal_store(0.0f, out + obase + m * L);
        return;
    }

    const float* __restrict__ R = rotmat + b * 9;
    const float R00 = R[0], R01 = R[1], R02 = R[2];
    const float R10 = R[3], R11 = R[4], R12 = R[5];
    const float R20 = R[6], R21 = R[7], R22 = R[8];
    const float lk  = -1.0f + (float)k * (2.0f / 127.0f);
    const float yc  = -1.0f + 64.0f * (2.0f / 127.0f);
    const float lj0 = -1.0f + (float)j0 * (2.0f / 127.0f);

    float gx = (lj0 * R00 + yc * R10 + lk * R20 + 1.0f) * 63.5f;
    float gy = (lj0 * R01 + yc * R11 + lk * R21 + 1.0f) * 63.5f;
    float gz = (lj0 * R02 + yc * R12 + lk * R22 + 1.0f) * 63.5f;

    PxF p[4]; bool any_alive = false;
    #pragma unroll
    for (int m = 0; m < 4; ++m) {
        p[m] = setup_pxf(gx, gy, gz, vis[m]);
        any_alive |= p[m].alive;
        gx += R00; gy += R01; gz += R02;
    }
    if (__ballot((int)any_alive) == 0ull) {
        #pragma unroll
        for (int m = 0; m < 4; ++m)
            __builtin_nontemporal_store(0.0f, out + obase + m * L);
        return;
    }

    f2v v[4][4];
    #pragma unroll
    for (int m = 0; m < 4; ++m) {
        v[m][0] = *(const f2v*)(vol + p[m].b00 + p[m].xe);
        v[m][1] = *(const f2v*)(vol + p[m].b01 + p[m].xe);
        v[m][2] = *(const f2v*)(vol + p[m].b10 + p[m].xe);
        v[m][3] = *(const f2v*)(vol + p[m].b11 + p[m].xe);
    }
    __builtin_amdgcn_sched_barrier(0);

    #pragma unroll
    for (int m = 0; m < 4; ++m) {
        const float r00 = p[m].wa * v[m][0].x + p[m].wb * v[m][0].y;
        const float r01 = p[m].wa * v[m][1].x + p[m].wb * v[m][1].y;
        const float r10 = p[m].wa * v[m][2].x + p[m].wb * v[m][2].y;
        const float r11 = p[m].wa * v[m][3].x + p[m].wb * v[m][3].y;
        const float res = p[m].wz0 * (p[m].wy0 * r00 + p[m].wy1 * r01)
                        + p[m].wz1 * (p[m].wy0 * r10 + p[m].wy1 * r11);
        __builtin_nontemporal_store(res, out + obase + m * L);
    }
}

extern "C" void kernel_launch(void* const* d_in, const int* in_sizes, int n_in,
                              void* d_out, int out_size, void* d_ws, size_t ws_size,
                              hipStream_t stream) {
    const float* rotmat = (const float*)d_in[0];
    const float* vol    = (const float*)d_in[1];
    float* out          = (float*)d_out;
    const int B = in_sizes[0] / 9;                // 2048

    if (ws_size >= TAB_BYTES) {
        uint4* T = (uint4*)d_ws;
        build_tab<<<dim3(NVOX / 256), dim3(256), 0, stream>>>(vol, T);
        const int nper = (B % 8 == 0) ? (B / 8) : 0;   // 0 -> identity map
        xfel_proj_t<<<dim3(16 * B), dim3(256), 0, stream>>>(rotmat, T, out, nper);
    } else {
        xfel_proj_f<<<dim3(16, B), dim3(256), 0, stream>>>(rotmat, vol, out);
    }
}